// Round 3
// baseline (215.438 us; speedup 1.0000x reference)
//
#include <hip/hip_runtime.h>

// Problem constants (B=8, C=512, H=W=64, K=19 classes)
#define NCLS   19
#define NB     8
#define NC     512
#define NHW    4096      // 64*64
#define EPSM   1e-6f     // mean denominator eps
#define EPSC   1e-8f     // cosine eps
#define NSEG   2         // pixel segments per channel-pair in k_sums

// Workspace layout (bytes)
#define OFF_LABELS   0u          // int32 [NB*NHW]
#define OFF_COUNTS   131072u     // float [NB*NCLS] ([b][k])
#define OFF_SUMS_S   132096u     // float [NB][NCLS][NC]  (means S after k_means)
#define OFF_SUMS_T   443392u     // float [NB][NCLS][NC]  (means T after k_means)
#define OFF_NORM_S   754688u     // float [NB*NCLS]
#define OFF_NORM_T   755712u     // float [NB*NCLS]
#define OFF_PART     756736u     // float [4 arrays][8 chunks][NB*NHW] (k_dots partials)
// k_sums segment-partials temporally reuse OFF_PART (consumed by k_means
// before k_dots writes its partials — same stream, serialized):
#define PSEG_BYTES   622592u     // NSEG*NB*NCLS*NC*4 bytes per tensor
// total = 756736 + 4*8*32768*4 = 4,951,040 B

// ---------------------------------------------------------------------------
// Wave-64 sum via DPP (VALU pipe only, no LDS). Result valid in lane 63.
template<int CTRL>
__device__ __forceinline__ float dpp_add(float x) {
    int y = __builtin_amdgcn_update_dpp(0, __float_as_int(x), CTRL, 0xf, 0xf, false);
    return x + __int_as_float(y);
}
__device__ __forceinline__ float wave64_sum(float x) {
    x = dpp_add<0x111>(x);   // row_shr:1
    x = dpp_add<0x112>(x);   // row_shr:2
    x = dpp_add<0x114>(x);   // row_shr:4
    x = dpp_add<0x118>(x);   // row_shr:8  -> lane15 of each row16 has row sum
    x = dpp_add<0x142>(x);   // row_bcast:15 -> lane31/63 have half sums
    x = dpp_add<0x143>(x);   // row_bcast:31 -> lane63 has total
    return x;
}

// ---------------------------------------------------------------------------
// Kernel 1: nearest-resize labels (512x512 -> 64x64) + per-batch class counts
__global__ __launch_bounds__(256) void k_labels(const int* __restrict__ target,
                                                int* __restrict__ labels,
                                                float* __restrict__ counts) {
    __shared__ int hist[NCLS];
    const int b = blockIdx.x;
    const int t = threadIdx.x;
    if (t < NCLS) hist[t] = 0;
    __syncthreads();
    const int* tb = target + (size_t)b * 512 * 512;
    #pragma unroll
    for (int i = 0; i < 16; ++i) {
        int n = t + i * 256;
        int y = n >> 6, x = n & 63;
        int l = tb[(y * 8) * 512 + x * 8];   // in_idx = floor(out_idx*512/64)
        labels[b * NHW + n] = l;
        if (l >= 0 && l < NCLS) atomicAdd(&hist[l], 1);
    }
    __syncthreads();
    if (t < NCLS) counts[b * NCLS + t] = (float)hist[t];
}

// ---------------------------------------------------------------------------
// Kernel 2: per-class channel sums, register-resident compare-select.
// Each WAVE owns 2 channels (S and T) over HALF the pixels (NSEG=2 split):
// grid 1024 blocks x 256 thr = 4096 waves = 4 waves/SIMD supply.
//
// OCCUPANCY HISTORY (this is the load-bearing decision):
//   (256,2): VGPR=96, but residency pinned at 2 waves/SIMD (occ 18.6%) —
//            the 2nd launch_bounds arg acts as a waves/EU CAP here; doubling
//            the grid (round 2) left duration flat at ~68 us.
//   (256,4): compiler clamps VGPR to 64 <= 256/4 -> ~880 MB scratch spill
//            traffic, 260 us (round 1). Occupancy DID rise to 43% though —
//            confirming the cap model.
//   (256) [this version]: no waves constraint. VGPR ~96 -> HW allows
//            floor(512/96)=5 waves/SIMD; grid supplies 4 -> fully resident.
// Segment partials are combined deterministically in k_means.
// Output layout: part[seg][b][k][c] (k-major) for coalesced downstream reads.
__global__ __launch_bounds__(256) void k_sums(const float* __restrict__ fS,
                                              const float* __restrict__ fT,
                                              const int* __restrict__ labels,
                                              float* __restrict__ partS,
                                              float* __restrict__ partT) {
    const int t = threadIdx.x;
    const int lane = t & 63;
    const int u = (blockIdx.x << 2) + (t >> 6);   // wave-unit 0..4095
    const int b = u >> 9;                          // 512 units per batch
    const int r = u & 511;
    const int c0 = (r >> 1) << 1;                  // channels c0, c0+1
    const int seg = r & 1;                         // pixel half
    const size_t base = ((size_t)(b * NC) + c0) * NHW;
    const float4* pS0 = (const float4*)(fS + base);
    const float4* pS1 = (const float4*)(fS + base + NHW);
    const float4* pT0 = (const float4*)(fT + base);
    const float4* pT1 = (const float4*)(fT + base + NHW);
    const int4* lab4 = (const int4*)(labels + b * NHW);

    float aS0[NCLS], aS1[NCLS], aT0[NCLS], aT1[NCLS];
    #pragma unroll
    for (int k = 0; k < NCLS; ++k) { aS0[k] = aS1[k] = aT0[k] = aT1[k] = 0.f; }

    #pragma unroll 2
    for (int i = 0; i < 8; ++i) {
        const int idx = (seg << 9) + lane + (i << 6);   // float4 index (4 pixels)
        const float4 vS0 = pS0[idx];
        const float4 vS1 = pS1[idx];
        const float4 vT0 = pT0[idx];
        const float4 vT1 = pT1[idx];
        const int4 l4 = lab4[idx];
        #pragma unroll
        for (int k = 0; k < NCLS; ++k) {
            const float m0 = (l4.x == k) ? 1.f : 0.f;
            const float m1 = (l4.y == k) ? 1.f : 0.f;
            const float m2 = (l4.z == k) ? 1.f : 0.f;
            const float m3 = (l4.w == k) ? 1.f : 0.f;
            aS0[k] += m0 * vS0.x + m1 * vS0.y + m2 * vS0.z + m3 * vS0.w;
            aS1[k] += m0 * vS1.x + m1 * vS1.y + m2 * vS1.z + m3 * vS1.w;
            aT0[k] += m0 * vT0.x + m1 * vT0.y + m2 * vT0.z + m3 * vT0.w;
            aT1[k] += m0 * vT1.x + m1 * vT1.y + m2 * vT1.z + m3 * vT1.w;
        }
    }
    // Cross-lane reduce each accumulator (DPP, lane 63 holds totals)
    #pragma unroll
    for (int k = 0; k < NCLS; ++k) {
        aS0[k] = wave64_sum(aS0[k]);
        aS1[k] = wave64_sum(aS1[k]);
        aT0[k] = wave64_sum(aT0[k]);
        aT1[k] = wave64_sum(aT1[k]);
    }
    if (lane == 63) {
        const size_t segoff = (size_t)seg * (NB * NCLS);
        #pragma unroll
        for (int k = 0; k < NCLS; ++k) {
            float2* dS = (float2*)(partS + (segoff + (size_t)(b * NCLS + k)) * NC + c0);
            float2* dT = (float2*)(partT + (segoff + (size_t)(b * NCLS + k)) * NC + c0);
            *dS = make_float2(aS0[k], aS1[k]);
            *dT = make_float2(aT0[k], aT1[k]);
        }
    }
}

// ---------------------------------------------------------------------------
// Kernel 3: combine segment partials, means = sum/(count+eps), per-(b,k)
// center norms. One wave per (b,k); all layouts [b][k][c] -> coalesced.
// Deterministic summation order (seg0 + seg1).
__global__ __launch_bounds__(64) void k_means(const float* __restrict__ partS,
                                              const float* __restrict__ partT,
                                              float* __restrict__ meansS,
                                              float* __restrict__ meansT,
                                              const float* __restrict__ counts,
                                              float* __restrict__ normS,
                                              float* __restrict__ normT) {
    const int bk = blockIdx.x;
    const int t = threadIdx.x;
    const float inv = 1.f / (counts[bk] + EPSM);
    const size_t s0 = (size_t)bk * NC;
    const size_t s1 = (size_t)(NB * NCLS + bk) * NC;
    float aS = 0.f, aT = 0.f;
    #pragma unroll
    for (int i = 0; i < NC / 64; ++i) {
        const int c = t + i * 64;
        float mS = (partS[s0 + c] + partS[s1 + c]) * inv;
        float mT = (partT[s0 + c] + partT[s1 + c]) * inv;
        meansS[s0 + c] = mS; aS += mS * mS;
        meansT[s0 + c] = mT; aT += mT * mT;
    }
    aS = wave64_sum(aS);
    aT = wave64_sum(aT);
    if (t == 63) { normS[bk] = sqrtf(aS); normT[bk] = sqrtf(aT); }
}

// ---------------------------------------------------------------------------
// Kernel 4: per-pixel dot(f, mean[lab]) and ||f||^2, atomic-free.
// Grid: 8 b x 16 pixel-tiles x 8 c-chunks = 1024 blocks.
// Means tile in LDS as [class][65] -> gather bank = (l+ci)%32, conflict-free.
#define CCH 64
__global__ __launch_bounds__(256) void k_dots(const float* __restrict__ fS,
                                              const float* __restrict__ fT,
                                              const float* __restrict__ meansS,
                                              const float* __restrict__ meansT,
                                              const int* __restrict__ labels,
                                              float* __restrict__ part) {
    __shared__ float mS[NCLS * 65];
    __shared__ float mT[NCLS * 65];
    const int blk = blockIdx.x;
    const int chunk = blk & 7;
    const int tile  = (blk >> 3) & 15;
    const int b     = blk >> 7;
    const int t = threadIdx.x;
    const int c0 = chunk * CCH;
    const int n = tile * 256 + t;

    for (int i = t; i < NCLS * CCH; i += 256) {
        const int k = i >> 6, j = i & 63;
        mS[k * 65 + j] = meansS[((size_t)(b * NCLS + k)) * NC + c0 + j];
        mT[k * 65 + j] = meansT[((size_t)(b * NCLS + k)) * NC + c0 + j];
    }
    __syncthreads();

    const int l = labels[b * NHW + n];
    const int lc = (l >= 0 && l < NCLS) ? l : 0;
    const float* pS = fS + ((size_t)(b * NC + c0)) * NHW + n;
    const float* pT = fT + ((size_t)(b * NC + c0)) * NHW + n;
    float dS = 0.f, nS = 0.f, dT = 0.f, nT = 0.f;
    #pragma unroll 8
    for (int ci = 0; ci < CCH; ++ci) {
        const float vS = pS[(size_t)ci * NHW];
        const float vT = pT[(size_t)ci * NHW];
        const float ms = mS[lc * 65 + ci];
        const float mt = mT[lc * 65 + ci];
        dS += vS * ms; nS += vS * vS;
        dT += vT * mt; nT += vT * vT;
    }
    const int p = b * NHW + n;
    part[((size_t)(0 * 8 + chunk)) * (NB * NHW) + p] = dS;
    part[((size_t)(1 * 8 + chunk)) * (NB * NHW) + p] = nS;
    part[((size_t)(2 * 8 + chunk)) * (NB * NHW) + p] = dT;
    part[((size_t)(3 * 8 + chunk)) * (NB * NHW) + p] = nT;
}

// ---------------------------------------------------------------------------
// Kernel 5: combine partials, cosines, MSE reduce.
__global__ __launch_bounds__(256) void k_final(const float* __restrict__ part,
                                               const int* __restrict__ labels,
                                               const float* __restrict__ normS,
                                               const float* __restrict__ normT,
                                               float* __restrict__ out) {
    __shared__ float red[4];
    const int p = blockIdx.x * 256 + threadIdx.x;
    const int b = p >> 12;
    float dS = 0.f, nS = 0.f, dT = 0.f, nT = 0.f;
    #pragma unroll
    for (int ch = 0; ch < 8; ++ch) {
        dS += part[((size_t)(0 * 8 + ch)) * (NB * NHW) + p];
        nS += part[((size_t)(1 * 8 + ch)) * (NB * NHW) + p];
        dT += part[((size_t)(2 * 8 + ch)) * (NB * NHW) + p];
        nT += part[((size_t)(3 * 8 + ch)) * (NB * NHW) + p];
    }
    const int l = labels[p];
    float val = 0.f;
    if (l >= 0 && l < NCLS) {
        float cS = dS / (fmaxf(sqrtf(nS), EPSC) * fmaxf(normS[b * NCLS + l], EPSC));
        float cT = dT / (fmaxf(sqrtf(nT), EPSC) * fmaxf(normT[b * NCLS + l], EPSC));
        float d = cS - cT;
        val = d * d;
    }
    val = wave64_sum(val);
    if ((threadIdx.x & 63) == 63) red[threadIdx.x >> 6] = val;
    __syncthreads();
    if (threadIdx.x == 0)
        atomicAdd(out, (red[0] + red[1] + red[2] + red[3]) * (1.f / (NB * NHW)));
}

// ---------------------------------------------------------------------------
extern "C" void kernel_launch(void* const* d_in, const int* in_sizes, int n_in,
                              void* d_out, int out_size, void* d_ws, size_t ws_size,
                              hipStream_t stream) {
    (void)in_sizes; (void)n_in; (void)out_size; (void)ws_size;
    const float* fS     = (const float*)d_in[0];
    const float* fT     = (const float*)d_in[1];
    const int*   target = (const int*)d_in[2];

    char* ws = (char*)d_ws;
    int*   labels = (int*)  (ws + OFF_LABELS);
    float* counts = (float*)(ws + OFF_COUNTS);
    float* meansS = (float*)(ws + OFF_SUMS_S);
    float* meansT = (float*)(ws + OFF_SUMS_T);
    float* normS  = (float*)(ws + OFF_NORM_S);
    float* normT  = (float*)(ws + OFF_NORM_T);
    float* part   = (float*)(ws + OFF_PART);
    // k_sums segment partials: temporal reuse of the OFF_PART region
    // (k_means consumes them before k_dots overwrites — same stream).
    float* partS  = (float*)(ws + OFF_PART);
    float* partT  = (float*)(ws + OFF_PART + PSEG_BYTES);

    hipMemsetAsync(d_out, 0, sizeof(float), stream);

    k_labels<<<NB, 256, 0, stream>>>(target, labels, counts);
    k_sums  <<<NB * NC / 4, 256, 0, stream>>>(fS, fT, labels, partS, partT);
    k_means <<<NB * NCLS, 64, 0, stream>>>(partS, partT, meansS, meansT, counts,
                                           normS, normT);
    k_dots  <<<NB * 16 * 8, 256, 0, stream>>>(fS, fT, meansS, meansT, labels, part);
    k_final <<<NB * NHW / 256, 256, 0, stream>>>(part, labels, normS, normT,
                                                 (float*)d_out);
}

// Round 4
// 206.868 us; speedup vs baseline: 1.0414x; 1.0414x over previous
//
#include <hip/hip_runtime.h>

// Problem constants (B=8, C=512, H=W=64, K=19 classes)
#define NCLS   19
#define NB     8
#define NC     512
#define NHW    4096      // 64*64
#define EPSM   1e-6f     // mean denominator eps
#define EPSC   1e-8f     // cosine eps
#define NSEG   2         // pixel segments per channel-pair in k_sums
#define KPW    5         // classes per wave in k_sums (4 waves: 5/5/5/4+pad)

// Workspace layout (bytes)
#define OFF_LABELS   0u          // int32 [NB*NHW]
#define OFF_COUNTS   131072u     // float [NB*NCLS] ([b][k])
#define OFF_SUMS_S   132096u     // float [NB][NCLS][NC]  (means S after k_means)
#define OFF_SUMS_T   443392u     // float [NB][NCLS][NC]  (means T after k_means)
#define OFF_NORM_S   754688u     // float [NB*NCLS]
#define OFF_NORM_T   755712u     // float [NB*NCLS]
#define OFF_PART     756736u     // float [4 arrays][8 chunks][NB*NHW] (k_dots partials)
// k_sums segment-partials temporally reuse OFF_PART (consumed by k_means
// before k_dots writes its partials — same stream, serialized):
#define PSEG_BYTES   622592u     // NSEG*NB*NCLS*NC*4 bytes per tensor
// total = 756736 + 4*8*32768*4 = 4,951,040 B

// ---------------------------------------------------------------------------
// Wave-64 sum via DPP (VALU pipe only, no LDS). Result valid in lane 63.
template<int CTRL>
__device__ __forceinline__ float dpp_add(float x) {
    int y = __builtin_amdgcn_update_dpp(0, __float_as_int(x), CTRL, 0xf, 0xf, false);
    return x + __int_as_float(y);
}
__device__ __forceinline__ float wave64_sum(float x) {
    x = dpp_add<0x111>(x);   // row_shr:1
    x = dpp_add<0x112>(x);   // row_shr:2
    x = dpp_add<0x114>(x);   // row_shr:4
    x = dpp_add<0x118>(x);   // row_shr:8  -> lane15 of each row16 has row sum
    x = dpp_add<0x142>(x);   // row_bcast:15 -> lane31/63 have half sums
    x = dpp_add<0x143>(x);   // row_bcast:31 -> lane63 has total
    return x;
}

// ---------------------------------------------------------------------------
// Kernel 1: nearest-resize labels (512x512 -> 64x64) + per-batch class counts
__global__ __launch_bounds__(256) void k_labels(const int* __restrict__ target,
                                                int* __restrict__ labels,
                                                float* __restrict__ counts) {
    __shared__ int hist[NCLS];
    const int b = blockIdx.x;
    const int t = threadIdx.x;
    if (t < NCLS) hist[t] = 0;
    __syncthreads();
    const int* tb = target + (size_t)b * 512 * 512;
    #pragma unroll
    for (int i = 0; i < 16; ++i) {
        int n = t + i * 256;
        int y = n >> 6, x = n & 63;
        int l = tb[(y * 8) * 512 + x * 8];   // in_idx = floor(out_idx*512/64)
        labels[b * NHW + n] = l;
        if (l >= 0 && l < NCLS) atomicAdd(&hist[l], 1);
    }
    __syncthreads();
    if (t < NCLS) counts[b * NCLS + t] = (float)hist[t];
}

// ---------------------------------------------------------------------------
// Kernel 2: per-class channel sums. CLASS-SPLIT-ACROSS-WAVES design.
//
// RESIDENCY MODEL (fitted to rounds 0-3, all four configs explained):
//   resident waves/SIMD = floor(256 / VGPR_Count)   [256-reg pool, not 512]
//     VGPR=96 -> 2/SIMD (occ 19%, rounds 0/2/3 — grid supply irrelevant)
//     VGPR=64 -> 4/SIMD (occ 43%, round 1)
//   and __launch_bounds__(256,W) clamps VGPR to 256/W (round 1: W=4 -> 64).
// The old 76-accumulator wave (2ch x S,T x 19cls) has a ~96-VGPR floor ->
// pinned at 2 waves/SIMD, latency-bound (VALUBusy 38%, HBM 13%).
//
// New structure: block of 4 waves owns one (b, channel-pair, seg); wave w
// accumulates only classes [5w, 5w+5) (wave 3: k=19 pad never matches, write
// guarded). Masks for each class computed by exactly ONE wave -> total VALU
// unchanged. Accumulators/wave: 4 arrays x KPW=5 = 20 -> natural VGPR ~56.
// All 4 waves read identical data -> L1/L2 broadcast absorbs the 4x issue.
// Grid: NB*(NC/2)*NSEG = 4096 blocks x 4 waves; residency 4/SIMD (2x round 0).
__global__ __launch_bounds__(256, 4) void k_sums(const float* __restrict__ fS,
                                                 const float* __restrict__ fT,
                                                 const int* __restrict__ labels,
                                                 float* __restrict__ partS,
                                                 float* __restrict__ partT) {
    const int t = threadIdx.x;
    const int lane = t & 63;
    const int w = t >> 6;                          // wave 0..3 -> class group
    const int blk = blockIdx.x;                    // 0..4095
    const int b   = blk >> 9;                      // 512 blocks per batch
    const int r   = blk & 511;
    const int c0  = (r >> 1) << 1;                 // channels c0, c0+1
    const int seg = r & 1;                         // pixel half
    const int k0  = w * KPW;                       // first class of this wave

    const size_t base = ((size_t)(b * NC) + c0) * NHW;
    const float4* pS0 = (const float4*)(fS + base);
    const float4* pS1 = (const float4*)(fS + base + NHW);
    const float4* pT0 = (const float4*)(fT + base);
    const float4* pT1 = (const float4*)(fT + base + NHW);
    const int4* lab4 = (const int4*)(labels + b * NHW);

    float aS0[KPW], aS1[KPW], aT0[KPW], aT1[KPW];
    #pragma unroll
    for (int j = 0; j < KPW; ++j) { aS0[j] = aS1[j] = aT0[j] = aT1[j] = 0.f; }

    for (int i = 0; i < 8; ++i) {
        const int idx = (seg << 9) + lane + (i << 6);   // float4 index (4 pixels)
        const float4 vS0 = pS0[idx];
        const float4 vS1 = pS1[idx];
        const float4 vT0 = pT0[idx];
        const float4 vT1 = pT1[idx];
        const int4 l4 = lab4[idx];
        #pragma unroll
        for (int j = 0; j < KPW; ++j) {            // static acc index (no scratch)
            const int k = k0 + j;                  // runtime-uniform class id
            const float m0 = (l4.x == k) ? 1.f : 0.f;
            const float m1 = (l4.y == k) ? 1.f : 0.f;
            const float m2 = (l4.z == k) ? 1.f : 0.f;
            const float m3 = (l4.w == k) ? 1.f : 0.f;
            aS0[j] += m0 * vS0.x + m1 * vS0.y + m2 * vS0.z + m3 * vS0.w;
            aS1[j] += m0 * vS1.x + m1 * vS1.y + m2 * vS1.z + m3 * vS1.w;
            aT0[j] += m0 * vT0.x + m1 * vT0.y + m2 * vT0.z + m3 * vT0.w;
            aT1[j] += m0 * vT1.x + m1 * vT1.y + m2 * vT1.z + m3 * vT1.w;
        }
    }
    // Cross-lane reduce each accumulator (DPP, lane 63 holds totals)
    #pragma unroll
    for (int j = 0; j < KPW; ++j) {
        aS0[j] = wave64_sum(aS0[j]);
        aS1[j] = wave64_sum(aS1[j]);
        aT0[j] = wave64_sum(aT0[j]);
        aT1[j] = wave64_sum(aT1[j]);
    }
    if (lane == 63) {
        const size_t segoff = (size_t)seg * (NB * NCLS);
        #pragma unroll
        for (int j = 0; j < KPW; ++j) {
            const int k = k0 + j;
            if (k < NCLS) {                        // wave 3's pad class 19: skip
                float2* dS = (float2*)(partS + (segoff + (size_t)(b * NCLS + k)) * NC + c0);
                float2* dT = (float2*)(partT + (segoff + (size_t)(b * NCLS + k)) * NC + c0);
                *dS = make_float2(aS0[j], aS1[j]);
                *dT = make_float2(aT0[j], aT1[j]);
            }
        }
    }
}

// ---------------------------------------------------------------------------
// Kernel 3: combine segment partials, means = sum/(count+eps), per-(b,k)
// center norms. One wave per (b,k); all layouts [b][k][c] -> coalesced.
// Deterministic summation order (seg0 + seg1).
__global__ __launch_bounds__(64) void k_means(const float* __restrict__ partS,
                                              const float* __restrict__ partT,
                                              float* __restrict__ meansS,
                                              float* __restrict__ meansT,
                                              const float* __restrict__ counts,
                                              float* __restrict__ normS,
                                              float* __restrict__ normT) {
    const int bk = blockIdx.x;
    const int t = threadIdx.x;
    const float inv = 1.f / (counts[bk] + EPSM);
    const size_t s0 = (size_t)bk * NC;
    const size_t s1 = (size_t)(NB * NCLS + bk) * NC;
    float aS = 0.f, aT = 0.f;
    #pragma unroll
    for (int i = 0; i < NC / 64; ++i) {
        const int c = t + i * 64;
        float mS = (partS[s0 + c] + partS[s1 + c]) * inv;
        float mT = (partT[s0 + c] + partT[s1 + c]) * inv;
        meansS[s0 + c] = mS; aS += mS * mS;
        meansT[s0 + c] = mT; aT += mT * mT;
    }
    aS = wave64_sum(aS);
    aT = wave64_sum(aT);
    if (t == 63) { normS[bk] = sqrtf(aS); normT[bk] = sqrtf(aT); }
}

// ---------------------------------------------------------------------------
// Kernel 4: per-pixel dot(f, mean[lab]) and ||f||^2, atomic-free.
// Grid: 8 b x 16 pixel-tiles x 8 c-chunks = 1024 blocks.
// Means tile in LDS as [class][65] -> gather bank = (l+ci)%32, conflict-free.
#define CCH 64
__global__ __launch_bounds__(256) void k_dots(const float* __restrict__ fS,
                                              const float* __restrict__ fT,
                                              const float* __restrict__ meansS,
                                              const float* __restrict__ meansT,
                                              const int* __restrict__ labels,
                                              float* __restrict__ part) {
    __shared__ float mS[NCLS * 65];
    __shared__ float mT[NCLS * 65];
    const int blk = blockIdx.x;
    const int chunk = blk & 7;
    const int tile  = (blk >> 3) & 15;
    const int b     = blk >> 7;
    const int t = threadIdx.x;
    const int c0 = chunk * CCH;
    const int n = tile * 256 + t;

    for (int i = t; i < NCLS * CCH; i += 256) {
        const int k = i >> 6, j = i & 63;
        mS[k * 65 + j] = meansS[((size_t)(b * NCLS + k)) * NC + c0 + j];
        mT[k * 65 + j] = meansT[((size_t)(b * NCLS + k)) * NC + c0 + j];
    }
    __syncthreads();

    const int l = labels[b * NHW + n];
    const int lc = (l >= 0 && l < NCLS) ? l : 0;
    const float* pS = fS + ((size_t)(b * NC + c0)) * NHW + n;
    const float* pT = fT + ((size_t)(b * NC + c0)) * NHW + n;
    float dS = 0.f, nS = 0.f, dT = 0.f, nT = 0.f;
    #pragma unroll 8
    for (int ci = 0; ci < CCH; ++ci) {
        const float vS = pS[(size_t)ci * NHW];
        const float vT = pT[(size_t)ci * NHW];
        const float ms = mS[lc * 65 + ci];
        const float mt = mT[lc * 65 + ci];
        dS += vS * ms; nS += vS * vS;
        dT += vT * mt; nT += vT * vT;
    }
    const int p = b * NHW + n;
    part[((size_t)(0 * 8 + chunk)) * (NB * NHW) + p] = dS;
    part[((size_t)(1 * 8 + chunk)) * (NB * NHW) + p] = nS;
    part[((size_t)(2 * 8 + chunk)) * (NB * NHW) + p] = dT;
    part[((size_t)(3 * 8 + chunk)) * (NB * NHW) + p] = nT;
}

// ---------------------------------------------------------------------------
// Kernel 5: combine partials, cosines, MSE reduce.
__global__ __launch_bounds__(256) void k_final(const float* __restrict__ part,
                                               const int* __restrict__ labels,
                                               const float* __restrict__ normS,
                                               const float* __restrict__ normT,
                                               float* __restrict__ out) {
    __shared__ float red[4];
    const int p = blockIdx.x * 256 + threadIdx.x;
    const int b = p >> 12;
    float dS = 0.f, nS = 0.f, dT = 0.f, nT = 0.f;
    #pragma unroll
    for (int ch = 0; ch < 8; ++ch) {
        dS += part[((size_t)(0 * 8 + ch)) * (NB * NHW) + p];
        nS += part[((size_t)(1 * 8 + ch)) * (NB * NHW) + p];
        dT += part[((size_t)(2 * 8 + ch)) * (NB * NHW) + p];
        nT += part[((size_t)(3 * 8 + ch)) * (NB * NHW) + p];
    }
    const int l = labels[p];
    float val = 0.f;
    if (l >= 0 && l < NCLS) {
        float cS = dS / (fmaxf(sqrtf(nS), EPSC) * fmaxf(normS[b * NCLS + l], EPSC));
        float cT = dT / (fmaxf(sqrtf(nT), EPSC) * fmaxf(normT[b * NCLS + l], EPSC));
        float d = cS - cT;
        val = d * d;
    }
    val = wave64_sum(val);
    if ((threadIdx.x & 63) == 63) red[threadIdx.x >> 6] = val;
    __syncthreads();
    if (threadIdx.x == 0)
        atomicAdd(out, (red[0] + red[1] + red[2] + red[3]) * (1.f / (NB * NHW)));
}

// ---------------------------------------------------------------------------
extern "C" void kernel_launch(void* const* d_in, const int* in_sizes, int n_in,
                              void* d_out, int out_size, void* d_ws, size_t ws_size,
                              hipStream_t stream) {
    (void)in_sizes; (void)n_in; (void)out_size; (void)ws_size;
    const float* fS     = (const float*)d_in[0];
    const float* fT     = (const float*)d_in[1];
    const int*   target = (const int*)d_in[2];

    char* ws = (char*)d_ws;
    int*   labels = (int*)  (ws + OFF_LABELS);
    float* counts = (float*)(ws + OFF_COUNTS);
    float* meansS = (float*)(ws + OFF_SUMS_S);
    float* meansT = (float*)(ws + OFF_SUMS_T);
    float* normS  = (float*)(ws + OFF_NORM_S);
    float* normT  = (float*)(ws + OFF_NORM_T);
    float* part   = (float*)(ws + OFF_PART);
    // k_sums segment partials: temporal reuse of the OFF_PART region
    // (k_means consumes them before k_dots overwrites — same stream).
    float* partS  = (float*)(ws + OFF_PART);
    float* partT  = (float*)(ws + OFF_PART + PSEG_BYTES);

    hipMemsetAsync(d_out, 0, sizeof(float), stream);

    k_labels<<<NB, 256, 0, stream>>>(target, labels, counts);
    k_sums  <<<NB * (NC / 2) * NSEG, 256, 0, stream>>>(fS, fT, labels, partS, partT);
    k_means <<<NB * NCLS, 64, 0, stream>>>(partS, partT, meansS, meansT, counts,
                                           normS, normT);
    k_dots  <<<NB * 16 * 8, 256, 0, stream>>>(fS, fT, meansS, meansT, labels, part);
    k_final <<<NB * NHW / 256, 256, 0, stream>>>(part, labels, normS, normT,
                                                 (float*)d_out);
}